// Round 1
// baseline (2019.667 us; speedup 1.0000x reference)
//
#include <hip/hip_runtime.h>
#include <math.h>

// EnvAwareRouter: B=524288, C=13, T=24, H=64, E=8, K=3, tau=1, eps=1e-10
// Inputs: contextual(B,C,T) f32, u(B,E) f32, tw1(T,H), tb1(H), tw2(H,1), tb2(1),
//         cw1(C,H), cb1(H), cw2(H,E), cb2(E)
// Output: concat[ mask(B,E), probs(B,E) ] f32
//
// Precision strategy: fc1 (dominant FLOPs) in fp32 — its error is attenuated
// ~20x through c_mlp's small weights. Everything downstream of the hidden
// gelu (fc2 accumulation, c_mlp, gumbel, softmax ordering) in fp64 so the
// top-3 selection matches the reference to ~1e-8, keeping expected mask
// flips << 1 across 524288 rows.

constexpr int Bn = 524288, Cn = 13, Tn = 24, Hn = 64, En = 8, Kn = 3;

__global__ __launch_bounds__(256) void router_kernel(
    const float* __restrict__ ctx, const float* __restrict__ u,
    const float* __restrict__ tw1, const float* __restrict__ tb1,
    const float* __restrict__ tw2, const float* __restrict__ tb2,
    const float* __restrict__ cw1, const float* __restrict__ cb1,
    const float* __restrict__ cw2, const float* __restrict__ cb2,
    float* __restrict__ out)
{
    __shared__ float tv_lds[256 * Cn];   // per-thread t values (stride 13: odd -> bank-free)

    const int b = blockIdx.x * 256 + threadIdx.x;
    if (b >= Bn) return;

    const float* xb = ctx + (long)b * (Cn * Tn);

    // ---- t_mlp per context c: t[c] = gelu(x @ tw1 + tb1) @ tw2 + tb2 ----
    for (int c = 0; c < Cn; ++c) {
        float x[Tn];
        const float4* xp = reinterpret_cast<const float4*>(xb + c * Tn);
        #pragma unroll
        for (int i = 0; i < Tn / 4; ++i) {
            float4 v = xp[i];
            x[4 * i + 0] = v.x; x[4 * i + 1] = v.y;
            x[4 * i + 2] = v.z; x[4 * i + 3] = v.w;
        }

        double acc = 0.0;
        for (int hb = 0; hb < Hn; hb += 8) {
            float a[8];
            #pragma unroll
            for (int j = 0; j < 8; ++j) a[j] = tb1[hb + j];
            #pragma unroll
            for (int t = 0; t < Tn; ++t) {
                const float xv = x[t];
                #pragma unroll
                for (int j = 0; j < 8; ++j)
                    a[j] = fmaf(xv, tw1[t * Hn + hb + j], a[j]);
            }
            #pragma unroll
            for (int j = 0; j < 8; ++j) {
                float e = erff(a[j] * 0.70710678118654752f);
                double g = 0.5 * (double)a[j] * (1.0 + (double)e);
                acc = fma(g, (double)tw2[hb + j], acc);
            }
        }
        tv_lds[threadIdx.x * Cn + c] = (float)(acc + (double)tb2[0]);
    }

    // pull t values back into registers (fully unrolled -> static indexing)
    double tv[Cn];
    #pragma unroll
    for (int c = 0; c < Cn; ++c) tv[c] = (double)tv_lds[threadIdx.x * Cn + c];

    // ---- c_mlp: logits = gelu(t @ cw1 + cb1) @ cw2 + cb2  (fp64) ----
    double logits[En];
    #pragma unroll
    for (int e = 0; e < En; ++e) logits[e] = (double)cb2[e];

    for (int h = 0; h < Hn; ++h) {
        double a = (double)cb1[h];
        #pragma unroll
        for (int c = 0; c < Cn; ++c)
            a = fma(tv[c], (double)cw1[c * Hn + h], a);
        float e32 = erff((float)(a * 0.7071067811865476));
        double g = 0.5 * a * (1.0 + (double)e32);
        #pragma unroll
        for (int e = 0; e < En; ++e)
            logits[e] = fma(g, (double)cw2[h * En + e], logits[e]);
    }

    // ---- gumbel + softmax (fp64) ----
    const float4* up = reinterpret_cast<const float4*>(u + (long)b * En);
    float4 u0 = up[0], u1 = up[1];
    float uv[En] = { u0.x, u0.y, u0.z, u0.w, u1.x, u1.y, u1.z, u1.w };

    double y[En];
    #pragma unroll
    for (int e = 0; e < En; ++e) {
        double uu = (double)uv[e];
        double g = -log(-log(uu) + 1e-10);
        y[e] = logits[e] + g;   // tau = 1
    }
    double m = y[0];
    #pragma unroll
    for (int e = 1; e < En; ++e) m = fmax(m, y[e]);
    double p[En], s = 0.0;
    #pragma unroll
    for (int e = 0; e < En; ++e) { p[e] = exp(y[e] - m); s += p[e]; }
    double inv = 1.0 / s;

    float probs[En];
    #pragma unroll
    for (int e = 0; e < En; ++e) probs[e] = (float)(p[e] * inv);

    // ---- top-3 k-hot mask (ties -> lowest index, matching lax.top_k) ----
    float mask[En];
    #pragma unroll
    for (int e = 0; e < En; ++e) mask[e] = 0.0f;
    double pv[En];
    #pragma unroll
    for (int e = 0; e < En; ++e) pv[e] = p[e];
    for (int k = 0; k < Kn; ++k) {
        int best = 0;
        double bv = pv[0];
        #pragma unroll
        for (int e = 1; e < En; ++e)
            if (pv[e] > bv) { bv = pv[e]; best = e; }
        mask[best] = 1.0f;
        pv[best] = -1.0e300;
    }

    // ---- stores: mask at [0, B*E), probs at [B*E, 2*B*E) ----
    float4* om = reinterpret_cast<float4*>(out + (long)b * En);
    om[0] = make_float4(mask[0], mask[1], mask[2], mask[3]);
    om[1] = make_float4(mask[4], mask[5], mask[6], mask[7]);
    float4* op = reinterpret_cast<float4*>(out + (long)Bn * En + (long)b * En);
    op[0] = make_float4(probs[0], probs[1], probs[2], probs[3]);
    op[1] = make_float4(probs[4], probs[5], probs[6], probs[7]);
}

extern "C" void kernel_launch(void* const* d_in, const int* in_sizes, int n_in,
                              void* d_out, int out_size, void* d_ws, size_t ws_size,
                              hipStream_t stream) {
    const float* ctx = (const float*)d_in[0];
    const float* u   = (const float*)d_in[1];
    const float* tw1 = (const float*)d_in[2];
    const float* tb1 = (const float*)d_in[3];
    const float* tw2 = (const float*)d_in[4];
    const float* tb2 = (const float*)d_in[5];
    const float* cw1 = (const float*)d_in[6];
    const float* cb1 = (const float*)d_in[7];
    const float* cw2 = (const float*)d_in[8];
    const float* cb2 = (const float*)d_in[9];
    float* out = (float*)d_out;

    dim3 grid(Bn / 256), block(256);
    router_kernel<<<grid, block, 0, stream>>>(ctx, u, tw1, tb1, tw2, tb2,
                                              cw1, cb1, cw2, cb2, out);
}

// Round 2
// 551.711 us; speedup vs baseline: 3.6607x; 3.6607x over previous
//
#include <hip/hip_runtime.h>
#include <math.h>

// EnvAwareRouter: B=524288, C=13, T=24, H=64, E=8, K=3, tau=1, eps=1e-10
// Output: concat[ mask(B,E), probs(B,E) ] f32
//
// R2 strategy: VALU-bound kernel; remove the non-FMA VALU overhead.
//  - branch-free A&S-7.1.26 erf (|eps|<=1.5e-7; error attenuated ~0.36x into
//    logits -> delta-logit < 1e-8, negligible vs flip budget)
//  - fp32 everywhere except: fc2/c_mlp accumulators (cheap fp64 FMAs) and the
//    16 gumbel logs (enter logits unattenuated -> keep OCML fp64 log)
//  - top-k done on y = logits + g directly (monotone with probs) in fp64
//  - softmax in fp32 (probs compared at bf16 tolerance 2e-2)
//  - fc1 h-blocked x16, x kept in registers, c-loop rolled (I$ control)

constexpr int Bn = 524288, Cn = 13, Tn = 24, Hn = 64, En = 8, Kn = 3;

#if __has_builtin(__builtin_amdgcn_rcpf)
#define RCPF(x) __builtin_amdgcn_rcpf(x)
#else
#define RCPF(x) (1.0f / (x))
#endif
#if __has_builtin(__builtin_amdgcn_exp2f)
#define EXP2F(x) __builtin_amdgcn_exp2f(x)
#else
#define EXP2F(x) exp2f(x)
#endif

// gelu(a) = a * (0.5 + 0.5*erf(a/sqrt(2))), erf via Abramowitz-Stegun 7.1.26
// (max abs err 1.5e-7), branch-free, sign via copysign.
__device__ __forceinline__ float fast_gelu(float a) {
    const float p  = 0.3275911f;
    const float c1 = 0.254829592f, c2 = -0.284496736f, c3 = 1.421413741f,
                c4 = -1.453152027f, c5 = 1.061405429f;
    float az = fabsf(a) * 0.70710678118654752f;          // |a|/sqrt(2)
    float t  = RCPF(fmaf(p, az, 1.0f));
    float poly = fmaf(fmaf(fmaf(fmaf(c5, t, c4), t, c3), t, c2), t, c1) * t;
    float ez = EXP2F(a * a * -0.72134752044448170f);     // exp(-a^2/2)
    float e  = fmaf(-poly, ez, 1.0f);                    // erf(|a|/sqrt2)
    float es = copysignf(e, a);
    return a * fmaf(es, 0.5f, 0.5f);
}

__global__ __launch_bounds__(256) void router_kernel(
    const float* __restrict__ ctx, const float* __restrict__ u,
    const float* __restrict__ tw1, const float* __restrict__ tb1,
    const float* __restrict__ tw2, const float* __restrict__ tb2,
    const float* __restrict__ cw1, const float* __restrict__ cb1,
    const float* __restrict__ cw2, const float* __restrict__ cb2,
    float* __restrict__ out)
{
    __shared__ float tv_lds[256 * Cn];   // stride 13 (odd) -> bank-conflict-free

    const int b = blockIdx.x * 256 + threadIdx.x;
    const float* xb = ctx + (long)b * (Cn * Tn);
    const float tb2v = tb2[0];

    // ---- t_mlp per context c (rolled c-loop for I$; body fully unrolled) ----
    #pragma unroll 1
    for (int c = 0; c < Cn; ++c) {
        float x[Tn];
        const float4* xp = reinterpret_cast<const float4*>(xb + c * Tn);
        #pragma unroll
        for (int i = 0; i < Tn / 4; ++i) {
            float4 v = xp[i];
            x[4 * i + 0] = v.x; x[4 * i + 1] = v.y;
            x[4 * i + 2] = v.z; x[4 * i + 3] = v.w;
        }

        double tacc = 0.0;
        #pragma unroll 1
        for (int hb = 0; hb < Hn; hb += 16) {
            float a[16];
            #pragma unroll
            for (int j = 0; j < 16; ++j) a[j] = tb1[hb + j];
            #pragma unroll
            for (int t = 0; t < Tn; ++t) {
                const float xv = x[t];
                #pragma unroll
                for (int j = 0; j < 16; ++j)
                    a[j] = fmaf(xv, tw1[t * Hn + hb + j], a[j]);
            }
            #pragma unroll
            for (int j = 0; j < 16; ++j) {
                float g = fast_gelu(a[j]);
                tacc = fma((double)g, (double)tw2[hb + j], tacc);
            }
        }
        tv_lds[threadIdx.x * Cn + c] = (float)(tacc + (double)tb2v);
    }

    // pull t values back (static offsets -> registers)
    float tv[Cn];
    #pragma unroll
    for (int c = 0; c < Cn; ++c) tv[c] = tv_lds[threadIdx.x * Cn + c];

    // ---- c_mlp: logits = gelu(t @ cw1 + cb1) @ cw2 + cb2 ----
    double logits[En];
    #pragma unroll
    for (int e = 0; e < En; ++e) logits[e] = (double)cb2[e];

    #pragma unroll 2
    for (int h = 0; h < Hn; ++h) {
        double a = (double)cb1[h];
        #pragma unroll
        for (int c = 0; c < Cn; ++c)
            a = fma((double)tv[c], (double)cw1[c * Hn + h], a);
        float g = fast_gelu((float)a);
        #pragma unroll
        for (int e = 0; e < En; ++e)
            logits[e] = fma((double)g, (double)cw2[h * En + e], logits[e]);
    }

    // ---- gumbel (fp64 logs: unattenuated), y = logits + g ----
    const float4* up = reinterpret_cast<const float4*>(u + (long)b * En);
    float4 u0 = up[0], u1 = up[1];
    float uv[En] = { u0.x, u0.y, u0.z, u0.w, u1.x, u1.y, u1.z, u1.w };

    double y[En];
    #pragma unroll
    for (int e = 0; e < En; ++e) {
        double w = -log((double)uv[e]);
        double g = -log(w + 1e-10);
        y[e] = logits[e] + g;   // tau = 1
    }

    // ---- softmax in fp32 (bf16-level tolerance on probs) ----
    double m = y[0];
    #pragma unroll
    for (int e = 1; e < En; ++e) m = fmax(m, y[e]);
    float p[En], s = 0.0f;
    #pragma unroll
    for (int e = 0; e < En; ++e) {
        p[e] = EXP2F((float)(y[e] - m) * 1.4426950408889634f);
        s += p[e];
    }
    float inv = RCPF(s);
    float probs[En];
    #pragma unroll
    for (int e = 0; e < En; ++e) probs[e] = p[e] * inv;

    // ---- top-3 k-hot on y (fp64 ordering == probs ordering) ----
    float mask[En];
    #pragma unroll
    for (int e = 0; e < En; ++e) mask[e] = 0.0f;
    double pv[En];
    #pragma unroll
    for (int e = 0; e < En; ++e) pv[e] = y[e];
    for (int k = 0; k < Kn; ++k) {
        int best = 0;
        double bv = pv[0];
        #pragma unroll
        for (int e = 1; e < En; ++e)
            if (pv[e] > bv) { bv = pv[e]; best = e; }
        mask[best] = 1.0f;
        pv[best] = -1.0e300;
    }

    // ---- stores ----
    float4* om = reinterpret_cast<float4*>(out + (long)b * En);
    om[0] = make_float4(mask[0], mask[1], mask[2], mask[3]);
    om[1] = make_float4(mask[4], mask[5], mask[6], mask[7]);
    float4* op = reinterpret_cast<float4*>(out + (long)Bn * En + (long)b * En);
    op[0] = make_float4(probs[0], probs[1], probs[2], probs[3]);
    op[1] = make_float4(probs[4], probs[5], probs[6], probs[7]);
}

extern "C" void kernel_launch(void* const* d_in, const int* in_sizes, int n_in,
                              void* d_out, int out_size, void* d_ws, size_t ws_size,
                              hipStream_t stream) {
    const float* ctx = (const float*)d_in[0];
    const float* u   = (const float*)d_in[1];
    const float* tw1 = (const float*)d_in[2];
    const float* tb1 = (const float*)d_in[3];
    const float* tw2 = (const float*)d_in[4];
    const float* tb2 = (const float*)d_in[5];
    const float* cw1 = (const float*)d_in[6];
    const float* cb1 = (const float*)d_in[7];
    const float* cw2 = (const float*)d_in[8];
    const float* cb2 = (const float*)d_in[9];
    float* out = (float*)d_out;

    dim3 grid(Bn / 256), block(256);
    router_kernel<<<grid, block, 0, stream>>>(ctx, u, tw1, tb1, tw2, tb2,
                                              cw1, cb1, cw2, cb2, out);
}

// Round 3
// 508.987 us; speedup vs baseline: 3.9680x; 1.0839x over previous
//
#include <hip/hip_runtime.h>
#include <math.h>

// EnvAwareRouter: B=524288, C=13, T=24, H=64, E=8, K=3, tau=1, eps=1e-10
// Output: concat[ mask(B,E), probs(B,E) ] f32
//
// R3: fix register starvation + drop unnecessary fp64.
//  - __launch_bounds__(256,4): 128-VGPR cap so x[24] stays resident across
//    the fc1 h-blocks (R2's VGPR=32 forced 4x re-load of x + mov shuffling
//    -> ~2.2x VALU instruction bloat at VALUBusy~100%)
//  - fc2 + c_mlp in fp32 (error budget: delta-logit ~3e-8, E[flips]~0.03)
//  - fp64 kept ONLY for the 16 gumbel logs (unattenuated, dg/dw up to 1e6)
//    and the y = logits + g top-k ordering
//  - A&S-7.1.26 erf gelu (|eps|<=1.5e-7), branch-free

constexpr int Bn = 524288, Cn = 13, Tn = 24, Hn = 64, En = 8, Kn = 3;

#if __has_builtin(__builtin_amdgcn_rcpf)
#define RCPF(x) __builtin_amdgcn_rcpf(x)
#else
#define RCPF(x) (1.0f / (x))
#endif
#if __has_builtin(__builtin_amdgcn_exp2f)
#define EXP2F(x) __builtin_amdgcn_exp2f(x)
#else
#define EXP2F(x) exp2f(x)
#endif

// gelu(a) = a * (0.5 + 0.5*erf(a/sqrt(2))), erf via Abramowitz-Stegun 7.1.26
__device__ __forceinline__ float fast_gelu(float a) {
    const float p  = 0.3275911f;
    const float c1 = 0.254829592f, c2 = -0.284496736f, c3 = 1.421413741f,
                c4 = -1.453152027f, c5 = 1.061405429f;
    float az = fabsf(a) * 0.70710678118654752f;          // z = |a|/sqrt(2)
    float t  = RCPF(fmaf(p, az, 1.0f));
    float poly = fmaf(fmaf(fmaf(fmaf(c5, t, c4), t, c3), t, c2), t, c1) * t;
    float z2 = az * az;                                  // a^2/2
    float ez = EXP2F(z2 * -1.4426950408889634f);         // exp(-a^2/2)
    float e  = fmaf(-poly, ez, 1.0f);                    // erf(z)
    float es = copysignf(e, a);
    return a * fmaf(es, 0.5f, 0.5f);
}

__global__ __launch_bounds__(256, 4) void router_kernel(
    const float* __restrict__ ctx, const float* __restrict__ u,
    const float* __restrict__ tw1, const float* __restrict__ tb1,
    const float* __restrict__ tw2, const float* __restrict__ tb2,
    const float* __restrict__ cw1, const float* __restrict__ cb1,
    const float* __restrict__ cw2, const float* __restrict__ cb2,
    float* __restrict__ out)
{
    __shared__ float tv_lds[256 * Cn];   // stride 13 (odd) -> bank-conflict-free

    const int b = blockIdx.x * 256 + threadIdx.x;
    const float* xb = ctx + (long)b * (Cn * Tn);
    const float tb2v = tb2[0];

    // ---- t_mlp per context c: t[c] = gelu(x @ tw1 + tb1) @ tw2 + tb2 ----
    #pragma unroll 1
    for (int c = 0; c < Cn; ++c) {
        float x[Tn];
        const float4* xp = reinterpret_cast<const float4*>(xb + c * Tn);
        #pragma unroll
        for (int i = 0; i < Tn / 4; ++i) {
            float4 v = xp[i];
            x[4 * i + 0] = v.x; x[4 * i + 1] = v.y;
            x[4 * i + 2] = v.z; x[4 * i + 3] = v.w;
        }

        float tacc = 0.0f;
        #pragma unroll 1
        for (int hb = 0; hb < Hn; hb += 16) {
            float a[16];
            #pragma unroll
            for (int j = 0; j < 16; ++j) a[j] = tb1[hb + j];
            #pragma unroll
            for (int t = 0; t < Tn; ++t) {
                const float xv = x[t];
                #pragma unroll
                for (int j = 0; j < 16; ++j)
                    a[j] = fmaf(xv, tw1[t * Hn + hb + j], a[j]);
            }
            #pragma unroll
            for (int j = 0; j < 16; ++j)
                tacc = fmaf(fast_gelu(a[j]), tw2[hb + j], tacc);
        }
        tv_lds[threadIdx.x * Cn + c] = tacc + tb2v;
    }

    // pull t values back (static offsets -> registers)
    float tv[Cn];
    #pragma unroll
    for (int c = 0; c < Cn; ++c) tv[c] = tv_lds[threadIdx.x * Cn + c];

    // ---- c_mlp (fp32): logits = gelu(t @ cw1 + cb1) @ cw2 + cb2 ----
    float logits[En];
    #pragma unroll
    for (int e = 0; e < En; ++e) logits[e] = cb2[e];

    #pragma unroll 1
    for (int h = 0; h < Hn; ++h) {
        float a = cb1[h];
        #pragma unroll
        for (int c = 0; c < Cn; ++c)
            a = fmaf(tv[c], cw1[c * Hn + h], a);
        float g = fast_gelu(a);
        #pragma unroll
        for (int e = 0; e < En; ++e)
            logits[e] = fmaf(g, cw2[h * En + e], logits[e]);
    }

    // ---- gumbel (fp64 logs: unattenuated), y = logits + g ----
    const float4* up = reinterpret_cast<const float4*>(u + (long)b * En);
    float4 u0 = up[0], u1 = up[1];
    float uv[En] = { u0.x, u0.y, u0.z, u0.w, u1.x, u1.y, u1.z, u1.w };

    double y[En];
    #pragma unroll
    for (int e = 0; e < En; ++e) {
        double w = -log((double)uv[e]);
        double g = -log(w + 1e-10);
        y[e] = (double)logits[e] + g;   // tau = 1
    }

    // ---- softmax in fp32 (probs compared at bf16 tolerance) ----
    double m = y[0];
    #pragma unroll
    for (int e = 1; e < En; ++e) m = fmax(m, y[e]);
    float p[En], s = 0.0f;
    #pragma unroll
    for (int e = 0; e < En; ++e) {
        p[e] = EXP2F((float)(y[e] - m) * 1.4426950408889634f);
        s += p[e];
    }
    float inv = RCPF(s);
    float probs[En];
    #pragma unroll
    for (int e = 0; e < En; ++e) probs[e] = p[e] * inv;

    // ---- top-3 k-hot on y (fp64 ordering == probs ordering) ----
    float mask[En];
    #pragma unroll
    for (int e = 0; e < En; ++e) mask[e] = 0.0f;
    double pv[En];
    #pragma unroll
    for (int e = 0; e < En; ++e) pv[e] = y[e];
    for (int k = 0; k < Kn; ++k) {
        int best = 0;
        double bv = pv[0];
        #pragma unroll
        for (int e = 1; e < En; ++e)
            if (pv[e] > bv) { bv = pv[e]; best = e; }
        mask[best] = 1.0f;
        pv[best] = -1.0e300;
    }

    // ---- stores ----
    float4* om = reinterpret_cast<float4*>(out + (long)b * En);
    om[0] = make_float4(mask[0], mask[1], mask[2], mask[3]);
    om[1] = make_float4(mask[4], mask[5], mask[6], mask[7]);
    float4* op = reinterpret_cast<float4*>(out + (long)Bn * En + (long)b * En);
    op[0] = make_float4(probs[0], probs[1], probs[2], probs[3]);
    op[1] = make_float4(probs[4], probs[5], probs[6], probs[7]);
}

extern "C" void kernel_launch(void* const* d_in, const int* in_sizes, int n_in,
                              void* d_out, int out_size, void* d_ws, size_t ws_size,
                              hipStream_t stream) {
    const float* ctx = (const float*)d_in[0];
    const float* u   = (const float*)d_in[1];
    const float* tw1 = (const float*)d_in[2];
    const float* tb1 = (const float*)d_in[3];
    const float* tw2 = (const float*)d_in[4];
    const float* tb2 = (const float*)d_in[5];
    const float* cw1 = (const float*)d_in[6];
    const float* cb1 = (const float*)d_in[7];
    const float* cw2 = (const float*)d_in[8];
    const float* cb2 = (const float*)d_in[9];
    float* out = (float*)d_out;

    dim3 grid(Bn / 256), block(256);
    router_kernel<<<grid, block, 0, stream>>>(ctx, u, tw1, tb1, tw2, tb2,
                                              cw1, cb1, cw2, cb2, out);
}